// Round 3
// baseline (328.668 us; speedup 1.0000x reference)
//
#include <hip/hip_runtime.h>

typedef unsigned short u16;
typedef unsigned int u32;
typedef __attribute__((ext_vector_type(8))) short short8;   // 8 bf16 (4 VGPRs)
typedef __attribute__((ext_vector_type(4))) float floatx4;  // MFMA accumulator

__device__ __forceinline__ u16 f2bf(float f) {
  u32 u = __float_as_uint(f);
  u32 r = u + 0x7fffu + ((u >> 16) & 1u);   // round-to-nearest-even
  return (u16)(r >> 16);
}

// async global->LDS, 16B per lane. lds ptr must be wave-uniform base; HW
// writes lane i at base + i*16.
__device__ __forceinline__ void gload_lds16(const u16* g, u16* l) {
  __builtin_amdgcn_global_load_lds(
      (const __attribute__((address_space(1))) u32*)g,
      (__attribute__((address_space(3))) u32*)l, 16, 0, 0);
}

// raw barrier: no compiler-injected vmcnt drain (unlike __syncthreads)
__device__ __forceinline__ void bar() { __builtin_amdgcn_s_barrier(); }

// counted vmem wait, pinned so loads can't cross it (rule #18 analog)
#define WAITVM(N) do {                                        \
    __builtin_amdgcn_sched_barrier(0);                        \
    asm volatile("s_waitcnt vmcnt(" #N ")" ::: "memory");     \
    __builtin_amdgcn_sched_barrier(0);                        \
  } while (0)

// ---------------------------------------------------------------------------
// Fused cast (fp32->bf16) + transpose, vectorized. (unchanged)
// ---------------------------------------------------------------------------
__global__ __launch_bounds__(256)
void cast_tr(const float* __restrict__ in, u16* __restrict__ cast_out,
             u16* __restrict__ tr_out, int rows, int cols, float scale,
             long bstride)
{
  __shared__ u16 tileT[64][66];
  const int b = blockIdx.z;
  in += (long)b * bstride;
  if (cast_out) cast_out += (long)b * bstride;
  tr_out += (long)b * bstride;
  const int r0 = blockIdx.y * 64, c0 = blockIdx.x * 64;
  const int tid = threadIdx.x;

  {
    const int i0 = tid >> 4;
    const int c4 = (tid & 15) * 4;
    #pragma unroll
    for (int rr = 0; rr < 4; ++rr) {
      const int r = i0 + 16 * rr;
      const float4 v = *(const float4*)&in[(long)(r0 + r) * cols + c0 + c4];
      ushort4 h;
      h.x = f2bf(v.x * scale); h.y = f2bf(v.y * scale);
      h.z = f2bf(v.z * scale); h.w = f2bf(v.w * scale);
      if (cast_out)
        *(ushort4*)&cast_out[(long)(r0 + r) * cols + c0 + c4] = h;
      tileT[c4 + 0][r] = h.x;
      tileT[c4 + 1][r] = h.y;
      tileT[c4 + 2][r] = h.z;
      tileT[c4 + 3][r] = h.w;
    }
  }
  __syncthreads();
  {
    const int cb = tid >> 5;
    const int rh = tid & 31;
    #pragma unroll
    for (int m = 0; m < 8; ++m) {
      const int c = cb * 8 + m;
      const u32 pair = *(const u32*)&tileT[c][rh * 2];
      *(u32*)&tr_out[(long)(c0 + c) * rows + r0 + rh * 2] = pair;
    }
  }
}

// ---------------------------------------------------------------------------
// 256x256 deep-pipelined NT GEMM: C = A[M,K] * Bt[N,K]^T, bf16 in, fp32 acc.
// 512 threads = 8 waves. Per-wave output: four 64x32 quadrants at
// (qm*128 + (w>>2)*64, qn*128 + (w&3)*32), quadrant snake
// (0,0)->(0,1)->(1,1)->(1,0). Block-wide, phase p consumes exactly ONE
// M-half of A / N-half of B:
//   p0: A-h0 + B-h0 (12 ds_read_b128)   p1: B-h1 (4)   p2: A-h1 (8)  p3: none
// (A frags cached across 2 phases, B-h0 frags cached p0->p3: 24 reads/tile.)
//
// LDS: 4 rolling half-buffers per operand (halfbuf = stream-index mod 4,
// 16 KiB each) = 128 KiB. A half dies one barrier after its phase; tile t
// stages tile t+2's halves into the just-dead buffers:
//   p1: A-h0 + B-h0(t+2)   p2: B-h1(t+2)   p3: A-h1(t+2)
// -> uniform 7-phase (~1400 cyc) prefetch distance. ONE counted wait per
// tile: s_waitcnt vmcnt(8) at the p3 tail (before the tile barrier), so
// 8-16 loads stay in flight across every barrier — never drains to 0 in
// steady state (T4; m218: counted-vs-drain0 = +38..73%).
//
// Swizzle: stage source chunk (lane&7)^srow, linear LDS dest; read chunk
// jc ^ (row&7) — same involution both sides; 0 bank conflicts measured.
//
// MODE 0: bf16 out. MODE 1: bf16 out=exp(acc*escale), fp32 row sums into
// rsum (atomics). MODE 2: fp32 out = acc / rsum[row] + bias[col].
// ---------------------------------------------------------------------------
template<int MODE>
__global__ __launch_bounds__(512, 2)
void gemm256(const u16* __restrict__ A, const u16* __restrict__ Bt,
             void* __restrict__ Cout, const float* __restrict__ bias,
             float* __restrict__ rsum,
             int M, int N, int K, int lda, int ldb, int ldc,
             long sA, long sB, long sC, float escale)
{
  __shared__ __align__(16) u16 ldsA[4 * 8192];   // 4 half-bufs x 128x64
  __shared__ __align__(16) u16 ldsB[4 * 8192];

  const int bz = blockIdx.z;
  A  += (long)bz * sA;
  Bt += (long)bz * sB;

  const int tid  = threadIdx.x;
  const int wave = tid >> 6;
  const int lane = tid & 63;

  // GROUP_M=8 pid swizzle for L2 strip reuse
  const int nbx = gridDim.x, nby = gridDim.y;
  const int pid  = blockIdx.y * nbx + blockIdx.x;
  const int band = 8 * nbx;
  const int gid  = pid / band;
  const int fm   = gid * 8;
  const int gsz  = min(nby - fm, 8);
  const int pm   = fm + (pid % band) % gsz;
  const int pn   = (pid % band) / gsz;
  const int tileM = pm * 256;
  const int tileN = pn * 256;

  // staging: per gload a wave covers 8 rows x 8 chunks(16B); per half-tile
  // (128 rows) each wave does 2 gloads covering rows wave*16 + [0,16).
  const int srow = lane >> 3;
  const int sjj  = (lane & 7) ^ srow;         // swizzled source chunk
  const u16* pA = A  + (long)(tileM + wave * 16 + srow) * lda + sjj * 8;
  const u16* pB = Bt + (long)(tileN + wave * 16 + srow) * ldb + sjj * 8;
  const int wso = wave * 1024;                // wave dest offset in half-buf

  // stage A/B half h of K-tile kt into half-buffer (2*(kt&1) + h)
#define STG_A(kt, h) do {                                                  \
    u16* d = ldsA + ((((kt) & 1) * 2 + (h)) * 8192) + wso;                 \
    const u16* g = pA + (long)((h) * 128) * lda + (long)(kt) * 64;         \
    gload_lds16(g, d); gload_lds16(g + (long)8 * lda, d + 512);            \
  } while (0)
#define STG_B(kt, h) do {                                                  \
    u16* d = ldsB + ((((kt) & 1) * 2 + (h)) * 8192) + wso;                 \
    const u16* g = pB + (long)((h) * 128) * ldb + (long)(kt) * 64;         \
    gload_lds16(g, d); gload_lds16(g + (long)8 * ldb, d + 512);            \
  } while (0)

  // mfma coords
  const int wv2 = wave >> 2;       // M sub-band (0/1) -> 64 rows
  const int wv4 = wave & 3;        // N sub-band (0-3) -> 32 cols
  const int lc = lane & 15;        // frag row/col within 16
  const int lq = lane >> 4;        // quad
  const int x8 = lc & 7;

  // frag LDS offsets within a half-buffer (u16); mi/nj add 1024 (imm-folds)
  const int aoff0 = (wv2 * 64 + lc) * 64 + (((0 + lq) ^ x8) << 3);  // kh=0
  const int aoff1 = (wv2 * 64 + lc) * 64 + (((4 + lq) ^ x8) << 3);  // kh=1
  const int boff0 = (wv4 * 32 + lc) * 64 + (((0 + lq) ^ x8) << 3);
  const int boff1 = (wv4 * 32 + lc) * 64 + (((4 + lq) ^ x8) << 3);

  floatx4 accq[2][2][4][2];
  #pragma unroll
  for (int qm = 0; qm < 2; ++qm)
    #pragma unroll
    for (int qn = 0; qn < 2; ++qn)
      #pragma unroll
      for (int mi = 0; mi < 4; ++mi)
        #pragma unroll
        for (int nj = 0; nj < 2; ++nj)
          accq[qm][qn][mi][nj] = (floatx4){0.f, 0.f, 0.f, 0.f};

  const int NT = K >> 6;

  // prologue: stage tiles 0 and 1 (16 loads); wait oldest 8 (tile 0)
  STG_A(0, 0); STG_A(0, 1); STG_B(0, 0); STG_B(0, 1);
  STG_A(1, 0); STG_A(1, 1); STG_B(1, 0); STG_B(1, 1);
  WAITVM(8);
  bar();

#define MFMA_Q(QM, QN, BF)                                                 \
    __builtin_amdgcn_s_setprio(1);                                        \
    _Pragma("unroll")                                                     \
    for (int kh = 0; kh < 2; ++kh)                                        \
      _Pragma("unroll")                                                   \
      for (int mi = 0; mi < 4; ++mi)                                      \
        _Pragma("unroll")                                                 \
        for (int nj = 0; nj < 2; ++nj)                                    \
          accq[QM][QN][mi][nj] = __builtin_amdgcn_mfma_f32_16x16x32_bf16( \
              af[mi][kh], BF[nj][kh], accq[QM][QN][mi][nj], 0, 0, 0);     \
    __builtin_amdgcn_s_setprio(0);

  short8 af[4][2], bq0[2][2], bq1[2][2];

  for (int t = 0; t < NT; ++t) {
    const int s2 = (t & 1) * 2;
    const u16* As0 = ldsA + (s2 + 0) * 8192;
    const u16* As1 = ldsA + (s2 + 1) * 8192;
    const u16* Bs0 = ldsB + (s2 + 0) * 8192;
    const u16* Bs1 = ldsB + (s2 + 1) * 8192;
    const bool stg = (t + 2) < NT;

    // ---- p0 (qm0,qn0): read A-h0 + B-h0
    #pragma unroll
    for (int mi = 0; mi < 4; ++mi) {
      af[mi][0] = *(const short8*)&As0[aoff0 + mi * 1024];
      af[mi][1] = *(const short8*)&As0[aoff1 + mi * 1024];
    }
    #pragma unroll
    for (int nj = 0; nj < 2; ++nj) {
      bq0[nj][0] = *(const short8*)&Bs0[boff0 + nj * 1024];
      bq0[nj][1] = *(const short8*)&Bs0[boff1 + nj * 1024];
    }
    bar();
    MFMA_Q(0, 0, bq0);
    bar();

    // ---- p1 (qm0,qn1): read B-h1; stage A-h0 + B-h0 of t+2 (bufs died p0)
    #pragma unroll
    for (int nj = 0; nj < 2; ++nj) {
      bq1[nj][0] = *(const short8*)&Bs1[boff0 + nj * 1024];
      bq1[nj][1] = *(const short8*)&Bs1[boff1 + nj * 1024];
    }
    if (stg) { STG_A(t + 2, 0); STG_B(t + 2, 0); }
    bar();
    MFMA_Q(0, 1, bq1);
    bar();

    // ---- p2 (qm1,qn1): read A-h1; B-h1 cached; stage B-h1 of t+2
    #pragma unroll
    for (int mi = 0; mi < 4; ++mi) {
      af[mi][0] = *(const short8*)&As1[aoff0 + mi * 1024];
      af[mi][1] = *(const short8*)&As1[aoff1 + mi * 1024];
    }
    if (stg) { STG_B(t + 2, 1); }
    bar();
    MFMA_Q(1, 1, bq1);
    bar();

    // ---- p3 (qm1,qn0): all frags cached; stage A-h1 of t+2; counted tail
    if (stg) { STG_A(t + 2, 1); }
    bar();
    MFMA_Q(1, 0, bq0);
    if (t < NT - 1) {
      if (stg) { WAITVM(8); } else { WAITVM(0); }
      bar();   // wave-wait + barrier => ALL waves' next-tile stages landed
    }
  }

#undef STG_A
#undef STG_B
#undef MFMA_Q

  // epilogue: C/D layout col = lane&15, row = quad*4 + reg
  if (MODE == 0) {
    u16* C = (u16*)Cout + (long)bz * sC;
    #pragma unroll
    for (int qm = 0; qm < 2; ++qm)
      #pragma unroll
      for (int mi = 0; mi < 4; ++mi) {
        const int rb = tileM + qm * 128 + wv2 * 64 + mi * 16 + lq * 4;
        #pragma unroll
        for (int qn = 0; qn < 2; ++qn)
          #pragma unroll
          for (int nj = 0; nj < 2; ++nj) {
            const int col = tileN + qn * 128 + wv4 * 32 + nj * 16 + lc;
            #pragma unroll
            for (int r = 0; r < 4; ++r)
              C[(long)(rb + r) * ldc + col] = f2bf(accq[qm][qn][mi][nj][r]);
          }
      }
  } else if (MODE == 1) {
    u16* C = (u16*)Cout + (long)bz * sC;
    float* rs = rsum + (long)bz * M;
    #pragma unroll
    for (int qm = 0; qm < 2; ++qm)
      #pragma unroll
      for (int mi = 0; mi < 4; ++mi) {
        const int rb = tileM + qm * 128 + wv2 * 64 + mi * 16 + lq * 4;
        float rpart[4] = {0.f, 0.f, 0.f, 0.f};
        #pragma unroll
        for (int qn = 0; qn < 2; ++qn)
          #pragma unroll
          for (int nj = 0; nj < 2; ++nj) {
            const int col = tileN + qn * 128 + wv4 * 32 + nj * 16 + lc;
            #pragma unroll
            for (int r = 0; r < 4; ++r) {
              float e = __expf(accq[qm][qn][mi][nj][r] * escale);
              C[(long)(rb + r) * ldc + col] = f2bf(e);
              rpart[r] += e;
            }
          }
        #pragma unroll
        for (int r = 0; r < 4; ++r) {
          float v = rpart[r];
          v += __shfl_xor(v, 1, 64);
          v += __shfl_xor(v, 2, 64);
          v += __shfl_xor(v, 4, 64);
          v += __shfl_xor(v, 8, 64);
          if (lc == 0) atomicAdd(&rs[rb + r], v);
        }
      }
  } else {
    float* C = (float*)Cout + (long)bz * sC;
    const float* rs = rsum + (long)bz * M;
    #pragma unroll
    for (int qm = 0; qm < 2; ++qm)
      #pragma unroll
      for (int mi = 0; mi < 4; ++mi) {
        const int rb = tileM + qm * 128 + wv2 * 64 + mi * 16 + lq * 4;
        float inv[4];
        #pragma unroll
        for (int r = 0; r < 4; ++r) inv[r] = 1.0f / rs[rb + r];
        #pragma unroll
        for (int qn = 0; qn < 2; ++qn)
          #pragma unroll
          for (int nj = 0; nj < 2; ++nj) {
            const int col = tileN + qn * 128 + wv4 * 32 + nj * 16 + lc;
            const float bv = bias[col];
            #pragma unroll
            for (int r = 0; r < 4; ++r)
              C[(long)(rb + r) * ldc + col] = accq[qm][qn][mi][nj][r] * inv[r] + bv;
          }
      }
  }
}

// ---------------------------------------------------------------------------
extern "C" void kernel_launch(void* const* d_in, const int* in_sizes, int n_in,
                              void* d_out, int out_size, void* d_ws, size_t ws_size,
                              hipStream_t stream) {
  const float* x    = (const float*)d_in[0];   // [B,S,D] fp32
  const float* W    = (const float*)d_in[1];   // [D,D]   fp32
  const float* bias = (const float*)d_in[2];   // [D]     fp32
  float* out        = (float*)d_out;           // [B,S,D] fp32
  (void)in_sizes; (void)n_in; (void)out_size; (void)ws_size;

  const int B = 8, S = 2048, D = 1024;
  const long BSD = (long)B * S * D;            // 16,777,216

  // workspace layout (u16 elements): ~162 MiB + 64 KiB row sums
  u16* Xb  = (u16*)d_ws;            // [B,S,D] bf16 (x)
  u16* XbT = Xb  + BSD;             // [B,D,S] bf16 (x transposed per batch)
  u16* Qb  = XbT + BSD;             // [B,S,D] bf16 (Q, pre-scaled by 1/32)
  u16* Wt  = Qb  + BSD;             // [D,D]   bf16 (W^T * 1/sqrt(D))
  u16* Sc  = Wt  + (long)D * D;     // [B,S,S] bf16 (E = exp(scores), unnorm)
  float* rsum = (float*)(Sc + (long)B * S * S);  // [B,S] fp32 row sums

  dim3 blk(256);
  dim3 blk2(512);

  // zero row sums (re-poisoned before every timed call)
  hipMemsetAsync(rsum, 0, (size_t)B * S * sizeof(float), stream);

  // x -> Xb + XbT (scale 1), W -> Wt (scale 1/32 folded into Q)
  cast_tr<<<dim3(D/64, S/64, B), blk, 0, stream>>>(x, Xb, XbT, S, D, 1.0f, (long)S*D);
  cast_tr<<<dim3(D/64, D/64, 1), blk, 0, stream>>>(W, nullptr, Wt, D, D, 0.03125f, 0);

  // GEMM1: Qb[BS,D] = Xb[BS,D] @ Wt[D,D]^T  (batches flattened)
  gemm256<0><<<dim3(D/256, (B*S)/256, 1), blk2, 0, stream>>>(
      Xb, Wt, Qb, nullptr, nullptr, B*S, D, D, D, D, D, 0, 0, 0, 1.0f);

  // GEMM2: Sc[S,S] = exp(Qb[S,D] @ Xb[S,D]^T), rsum += row sums  per batch
  gemm256<1><<<dim3(S/256, S/256, B), blk2, 0, stream>>>(
      Qb, Xb, Sc, nullptr, rsum, S, S, D, D, D, S,
      (long)S*D, (long)S*D, (long)S*S, 1.0f);

  // GEMM3: out[S,D] = (Sc/rsum)[S,S] @ XbT[D,S]^T + bias  per batch, fp32 out
  gemm256<2><<<dim3(D/256, S/256, B), blk2, 0, stream>>>(
      Sc, XbT, out, bias, rsum, S, D, S, S, S, D,
      (long)S*S, (long)D*S, (long)S*D, 1.0f);
}

// Round 5
// 323.100 us; speedup vs baseline: 1.0172x; 1.0172x over previous
//
#include <hip/hip_runtime.h>

typedef unsigned short u16;
typedef unsigned int u32;
typedef __attribute__((ext_vector_type(8))) short short8;   // 8 bf16 (4 VGPRs)
typedef __attribute__((ext_vector_type(4))) float floatx4;  // MFMA accumulator

__device__ __forceinline__ u16 f2bf(float f) {
  u32 u = __float_as_uint(f);
  u32 r = u + 0x7fffu + ((u >> 16) & 1u);   // round-to-nearest-even
  return (u16)(r >> 16);
}

// async global->LDS, 16B per lane. lds ptr must be wave-uniform base; HW
// writes lane i at base + i*16.
__device__ __forceinline__ void gload_lds16(const u16* g, u16* l) {
  __builtin_amdgcn_global_load_lds(
      (const __attribute__((address_space(1))) u32*)g,
      (__attribute__((address_space(3))) u32*)l, 16, 0, 0);
}

// ---------------------------------------------------------------------------
// Fused cast (fp32->bf16) + transpose, vectorized. in: [rows, cols] fp32.
// cast_out (optional): bf16 same layout (ushort4 stores).
// tr_out: bf16 [cols, rows] (u32 = 2-element stores, coalesced along rows).
// Tile 64x64, 256 threads.
// ---------------------------------------------------------------------------
__global__ __launch_bounds__(256)
void cast_tr(const float* __restrict__ in, u16* __restrict__ cast_out,
             u16* __restrict__ tr_out, int rows, int cols, float scale,
             long bstride)
{
  // transposed tile: tileT[src_col][src_row], pad 66 (132B row, 33-bank shift)
  __shared__ u16 tileT[64][66];
  const int b = blockIdx.z;
  in += (long)b * bstride;
  if (cast_out) cast_out += (long)b * bstride;
  tr_out += (long)b * bstride;
  const int r0 = blockIdx.y * 64, c0 = blockIdx.x * 64;
  const int tid = threadIdx.x;

  // phase 1: read float4, cast, store ushort4, scatter to tileT
  {
    const int i0 = tid >> 4;          // 0..15 row group
    const int c4 = (tid & 15) * 4;    // col group of 4
    #pragma unroll
    for (int rr = 0; rr < 4; ++rr) {
      const int r = i0 + 16 * rr;
      const float4 v = *(const float4*)&in[(long)(r0 + r) * cols + c0 + c4];
      ushort4 h;
      h.x = f2bf(v.x * scale); h.y = f2bf(v.y * scale);
      h.z = f2bf(v.z * scale); h.w = f2bf(v.w * scale);
      if (cast_out)
        *(ushort4*)&cast_out[(long)(r0 + r) * cols + c0 + c4] = h;
      tileT[c4 + 0][r] = h.x;
      tileT[c4 + 1][r] = h.y;
      tileT[c4 + 2][r] = h.z;
      tileT[c4 + 3][r] = h.w;
    }
  }
  __syncthreads();

  // phase 2: write transposed, u32 (2 bf16) per store, lanes walk rows fast
  {
    const int cb = tid >> 5;          // 0..7
    const int rh = tid & 31;          // 0..31 (u32 position within 64 rows)
    #pragma unroll
    for (int m = 0; m < 8; ++m) {
      const int c = cb * 8 + m;
      const u32 pair = *(const u32*)&tileT[c][rh * 2];
      *(u32*)&tr_out[(long)(c0 + c) * rows + r0 + rh * 2] = pair;
    }
  }
}

// ---------------------------------------------------------------------------
// NT GEMM: C[M,N] = A[M,K] * Bt[N,K]^T, bf16 inputs, fp32 accumulate.
// Block tile = (MI*32) x (NJ*32), BK=64. 4 waves in 2x2; each wave MIxNJ
// tiles of 16x16x32 MFMA. LDS staged via global_load_lds(16B) with XOR
// chunk swizzle. GROUP_M=8 pid swizzle for L2 strip reuse.
//
// R4/R5: __launch_bounds__(256, 4) — was 3. LDS 32 KiB allows 5 blocks/CU,
// VGPR=64 allows 8 waves/SIMD; min-waves declaration was the binding
// occupancy cap (34.7% measured). 4 co-resident blocks hide the per-tile
// vmcnt(0)+barrier drain of each other (R1-R3 showed 256x256 deep pipelines
// all regress in this K=1024 / many-small-blocks regime; occupancy is the
// remaining lever at the proven 128^2 structure).
//
// MODE 0: plain bf16 out.
// MODE 1: bf16 out = exp(acc*escale); fp32 row sums into rsum (atomics).
// MODE 2: fp32 out = acc / rsum[row] + bias[col].
// ---------------------------------------------------------------------------
#define BK 64

template<int MODE, int MI, int NJ>
__global__ __launch_bounds__(256, 4)
void gemm_nt(const u16* __restrict__ A, const u16* __restrict__ Bt,
             void* __restrict__ Cout, const float* __restrict__ bias,
             float* __restrict__ rsum,
             int M, int N, int K, int lda, int ldb, int ldc,
             long sA, long sB, long sC, float escale)
{
  constexpr int BM = MI * 32;
  constexpr int BN = NJ * 32;
  __shared__ __align__(16) u16 As[BM * BK];
  __shared__ __align__(16) u16 Bs[BN * BK];

  const int bz = blockIdx.z;
  A  += (long)bz * sA;
  Bt += (long)bz * sB;

  const int tid  = threadIdx.x;
  const int wave = tid >> 6;
  const int lane = tid & 63;

  // GROUP_M=8 swizzle
  const int nbx = gridDim.x, nby = gridDim.y;
  const int pid  = blockIdx.y * nbx + blockIdx.x;
  const int band = 8 * nbx;
  const int gid  = pid / band;
  const int fm   = gid * 8;
  const int gsz  = min(nby - fm, 8);
  const int pm   = fm + (pid % band) % gsz;
  const int pn   = (pid % band) / gsz;
  const int tileM = pm * BM;
  const int tileN = pn * BN;

  // staging: per instruction a wave covers 8 rows x 8 chunks (16B each)
  const int srow = lane >> 3;      // 0..7 row within 8-row group
  const int sj   = lane & 7;       // 0..7 dest chunk
  const int sjj  = sj ^ srow;      // swizzled source chunk

  // wave quadrant + mfma lane coords
  const int wm = (wave >> 1) * (MI * 16);
  const int wn = (wave & 1) * (NJ * 16);
  const int lc = lane & 15;        // A row / B col / C col
  const int lq = lane >> 4;        // quad

  floatx4 acc[MI][NJ];
  #pragma unroll
  for (int i = 0; i < MI; ++i)
    #pragma unroll
    for (int j = 0; j < NJ; ++j)
      acc[i][j] = (floatx4){0.f, 0.f, 0.f, 0.f};

  for (int k0 = 0; k0 < K; k0 += BK) {
    #pragma unroll
    for (int s = 0; s < MI; ++s) {
      const int rb = (wave * MI + s) * 8;
      gload_lds16(A + (long)(tileM + rb + srow) * lda + k0 + sjj * 8,
                  &As[rb * BK]);
    }
    #pragma unroll
    for (int s = 0; s < NJ; ++s) {
      const int rb = (wave * NJ + s) * 8;
      gload_lds16(Bt + (long)(tileN + rb + srow) * ldb + k0 + sjj * 8,
                  &Bs[rb * BK]);
    }
    __syncthreads();   // drains vmcnt(0) -> LDS valid

    #pragma unroll
    for (int kk = 0; kk < BK; kk += 32) {
      const int jcb = (kk >> 3) + lq;       // logical chunk for this quad
      short8 af[MI], bf[NJ];
      #pragma unroll
      for (int i = 0; i < MI; ++i) {
        const int m = wm + i * 16 + lc;
        af[i] = *(const short8*)&As[m * BK + ((jcb ^ (m & 7)) << 3)];
      }
      #pragma unroll
      for (int j = 0; j < NJ; ++j) {
        const int n = wn + j * 16 + lc;
        bf[j] = *(const short8*)&Bs[n * BK + ((jcb ^ (n & 7)) << 3)];
      }
      #pragma unroll
      for (int i = 0; i < MI; ++i)
        #pragma unroll
        for (int j = 0; j < NJ; ++j)
          acc[i][j] = __builtin_amdgcn_mfma_f32_16x16x32_bf16(
                          af[i], bf[j], acc[i][j], 0, 0, 0);
    }
    __syncthreads();   // protect LDS before next stage
  }

  // epilogue: C/D layout col = lane&15, row = quad*4 + reg
  if (MODE == 0) {
    u16* C = (u16*)Cout + (long)bz * sC;
    #pragma unroll
    for (int i = 0; i < MI; ++i) {
      const int rb = tileM + wm + i * 16 + lq * 4;
      #pragma unroll
      for (int j = 0; j < NJ; ++j) {
        const int col = tileN + wn + j * 16 + lc;
        #pragma unroll
        for (int r = 0; r < 4; ++r)
          C[(long)(rb + r) * ldc + col] = f2bf(acc[i][j][r]);
      }
    }
  } else if (MODE == 1) {
    u16* C = (u16*)Cout + (long)bz * sC;
    float* rs = rsum + (long)bz * M;
    #pragma unroll
    for (int i = 0; i < MI; ++i) {
      const int rb = tileM + wm + i * 16 + lq * 4;
      float rpart[4] = {0.f, 0.f, 0.f, 0.f};
      #pragma unroll
      for (int j = 0; j < NJ; ++j) {
        const int col = tileN + wn + j * 16 + lc;
        #pragma unroll
        for (int r = 0; r < 4; ++r) {
          float e = __expf(acc[i][j][r] * escale);
          C[(long)(rb + r) * ldc + col] = f2bf(e);
          rpart[r] += e;
        }
      }
      #pragma unroll
      for (int r = 0; r < 4; ++r) {
        float s = rpart[r];
        s += __shfl_xor(s, 1, 64);
        s += __shfl_xor(s, 2, 64);
        s += __shfl_xor(s, 4, 64);
        s += __shfl_xor(s, 8, 64);
        if (lc == 0) atomicAdd(&rs[rb + r], s);
      }
    }
  } else {
    float* C = (float*)Cout + (long)bz * sC;
    const float* rs = rsum + (long)bz * M;
    #pragma unroll
    for (int i = 0; i < MI; ++i) {
      const int rb = tileM + wm + i * 16 + lq * 4;
      float inv[4];
      #pragma unroll
      for (int r = 0; r < 4; ++r) inv[r] = 1.0f / rs[rb + r];
      #pragma unroll
      for (int j = 0; j < NJ; ++j) {
        const int col = tileN + wn + j * 16 + lc;
        const float bv = bias[col];
        #pragma unroll
        for (int r = 0; r < 4; ++r)
          C[(long)(rb + r) * ldc + col] = acc[i][j][r] * inv[r] + bv;
      }
    }
  }
}

// ---------------------------------------------------------------------------
extern "C" void kernel_launch(void* const* d_in, const int* in_sizes, int n_in,
                              void* d_out, int out_size, void* d_ws, size_t ws_size,
                              hipStream_t stream) {
  const float* x    = (const float*)d_in[0];   // [B,S,D] fp32
  const float* W    = (const float*)d_in[1];   // [D,D]   fp32
  const float* bias = (const float*)d_in[2];   // [D]     fp32
  float* out        = (float*)d_out;           // [B,S,D] fp32
  (void)in_sizes; (void)n_in; (void)out_size; (void)ws_size;

  const int B = 8, S = 2048, D = 1024;
  const long BSD = (long)B * S * D;            // 16,777,216

  // workspace layout (u16 elements): ~162 MiB + 64 KiB row sums
  u16* Xb  = (u16*)d_ws;            // [B,S,D] bf16 (x)
  u16* XbT = Xb  + BSD;             // [B,D,S] bf16 (x transposed per batch)
  u16* Qb  = XbT + BSD;             // [B,S,D] bf16 (Q, pre-scaled by 1/32)
  u16* Wt  = Qb  + BSD;             // [D,D]   bf16 (W^T * 1/sqrt(D))
  u16* Sc  = Wt  + (long)D * D;     // [B,S,S] bf16 (E = exp(scores), unnorm)
  float* rsum = (float*)(Sc + (long)B * S * S);  // [B,S] fp32 row sums

  dim3 blk(256);

  // zero row sums (re-poisoned to 0xAA before every timed call)
  hipMemsetAsync(rsum, 0, (size_t)B * S * sizeof(float), stream);

  // x -> Xb + XbT (scale 1), W -> Wt (scale 1/32 folded into Q)
  cast_tr<<<dim3(D/64, S/64, B), blk, 0, stream>>>(x, Xb, XbT, S, D, 1.0f, (long)S*D);
  cast_tr<<<dim3(D/64, D/64, 1), blk, 0, stream>>>(W, nullptr, Wt, D, D, 0.03125f, 0);

  // GEMM1: Qb[BS,D] = Xb[BS,D] @ Wt[D,D]^T   (batches flattened)
  // 128x128 tile: 64x128 tried earlier regressed (compute/staging intensity
  // drops 64 -> 42.7, GEMM1 became staging-bound).
  gemm_nt<0, 4, 4><<<dim3(D/128, (B*S)/128, 1), blk, 0, stream>>>(
      Xb, Wt, Qb, nullptr, nullptr, B*S, D, D, D, D, D, 0, 0, 0, 1.0f);

  // GEMM2: Sc[S,S] = exp(Qb[S,D] @ Xb[S,D]^T), rsum += row sums  per batch
  gemm_nt<1, 4, 4><<<dim3(S/128, S/128, B), blk, 0, stream>>>(
      Qb, Xb, Sc, nullptr, rsum, S, S, D, D, D, S,
      (long)S*D, (long)S*D, (long)S*S, 1.0f);

  // GEMM3: out[S,D] = (Sc/rsum)[S,S] @ XbT[D,S]^T + bias  per batch, fp32 out
  gemm_nt<2, 4, 4><<<dim3(D/128, S/128, B), blk, 0, stream>>>(
      Sc, XbT, out, bias, rsum, S, D, S, S, S, D,
      (long)S*S, (long)D*S, (long)S*D, 1.0f);
}

// Round 6
// 321.150 us; speedup vs baseline: 1.0234x; 1.0061x over previous
//
#include <hip/hip_runtime.h>

typedef unsigned short u16;
typedef unsigned int u32;
typedef __attribute__((ext_vector_type(8))) short short8;   // 8 bf16 (4 VGPRs)
typedef __attribute__((ext_vector_type(4))) float floatx4;  // MFMA accumulator

__device__ __forceinline__ u16 f2bf(float f) {
  u32 u = __float_as_uint(f);
  u32 r = u + 0x7fffu + ((u >> 16) & 1u);   // round-to-nearest-even
  return (u16)(r >> 16);
}

// async global->LDS, 16B per lane. lds ptr must be wave-uniform base; HW
// writes lane i at base + i*16.
__device__ __forceinline__ void gload_lds16(const u16* g, u16* l) {
  __builtin_amdgcn_global_load_lds(
      (const __attribute__((address_space(1))) u32*)g,
      (__attribute__((address_space(3))) u32*)l, 16, 0, 0);
}

// ---------------------------------------------------------------------------
// Fused cast (fp32->bf16) + transpose tile worker. in: [rows, cols] fp32.
// cast_out (optional): bf16 same layout (ushort4 stores).
// tr_out: bf16 [cols, rows] (u32 = 2-element stores, coalesced along rows).
// Tile 64x64, 256 threads. tileT pad 66 (132B row, 33-bank shift).
// ---------------------------------------------------------------------------
__device__ __forceinline__ void cast_tr_tile(
    u16 (*tileT)[66], const float* __restrict__ in, u16* __restrict__ cast_out,
    u16* __restrict__ tr_out, int rows, int cols, float scale,
    int r0, int c0, int tid)
{
  // phase 1: read float4, cast, store ushort4, scatter to tileT
  {
    const int i0 = tid >> 4;          // 0..15 row group
    const int c4 = (tid & 15) * 4;    // col group of 4
    #pragma unroll
    for (int rr = 0; rr < 4; ++rr) {
      const int r = i0 + 16 * rr;
      const float4 v = *(const float4*)&in[(long)(r0 + r) * cols + c0 + c4];
      ushort4 h;
      h.x = f2bf(v.x * scale); h.y = f2bf(v.y * scale);
      h.z = f2bf(v.z * scale); h.w = f2bf(v.w * scale);
      if (cast_out)
        *(ushort4*)&cast_out[(long)(r0 + r) * cols + c0 + c4] = h;
      tileT[c4 + 0][r] = h.x;
      tileT[c4 + 1][r] = h.y;
      tileT[c4 + 2][r] = h.z;
      tileT[c4 + 3][r] = h.w;
    }
  }
  __syncthreads();

  // phase 2: write transposed, u32 (2 bf16) per store, lanes walk rows fast
  {
    const int cb = tid >> 5;          // 0..7
    const int rh = tid & 31;          // 0..31 (u32 position within 64 rows)
    #pragma unroll
    for (int m = 0; m < 8; ++m) {
      const int c = cb * 8 + m;
      const u32 pair = *(const u32*)&tileT[c][rh * 2];
      *(u32*)&tr_out[(long)(c0 + c) * rows + r0 + rh * 2] = pair;
    }
  }
}

// ---------------------------------------------------------------------------
// R6: single prep kernel replaces {memset rsum, cast_tr(x), cast_tr(W)} —
// 6 dispatches -> 4 total. Wall-vs-kernel-sum showed ~80 us of inter-
// dispatch overhead; this removes two slots. Grid (16, 32, 9):
//   z<8          : cast+transpose x batch z (S=2048 rows, D=1024 cols)
//   z=8, by<16   : cast+transpose W (scale 1/32 folded into Q)
//   z=8, by==16  : zero rsum (16 blocks x 256 thr x float4 = 64 KiB)
//   z=8, by>16   : no-op (240 empty blocks, negligible)
// rsum zeroing completes before GEMM2 (stream-ordered) -> safe.
// ---------------------------------------------------------------------------
__global__ __launch_bounds__(256)
void prep(const float* __restrict__ x, const float* __restrict__ W,
          u16* __restrict__ Xb, u16* __restrict__ XbT, u16* __restrict__ Wt,
          float* __restrict__ rsum)
{
  __shared__ u16 tileT[64][66];
  const int tid = threadIdx.x;
  const int bx = blockIdx.x, by = blockIdx.y, z = blockIdx.z;

  if (z < 8) {
    const long off = (long)z * 2048 * 1024;
    cast_tr_tile(tileT, x + off, Xb + off, XbT + off,
                 2048, 1024, 1.0f, by * 64, bx * 64, tid);
  } else if (by < 16) {
    cast_tr_tile(tileT, W, nullptr, Wt,
                 1024, 1024, 0.03125f, by * 64, bx * 64, tid);
  } else if (by == 16) {
    *(float4*)&rsum[(bx * 256 + tid) * 4] = (float4){0.f, 0.f, 0.f, 0.f};
  }
}

// ---------------------------------------------------------------------------
// NT GEMM: C[M,N] = A[M,K] * Bt[N,K]^T, bf16 inputs, fp32 accumulate.
// Block tile = (MI*32) x (NJ*32), BK=64. 4 waves in 2x2; each wave MIxNJ
// tiles of 16x16x32 MFMA. LDS staged via global_load_lds(16B) with XOR
// chunk swizzle. GROUP_M=8 pid swizzle for L2 strip reuse.
// Verified plateau: ~830 TF at K=1024 (R0-R5: three deep-pipeline rewrites
// and the occupancy knob all neutral-to-regressive; this 2-barrier 128^2
// structure is the measured local optimum for this shape).
// MODE 0: plain bf16 out.
// MODE 1: bf16 out = exp(acc*escale); fp32 row sums into rsum (atomics).
// MODE 2: fp32 out = acc / rsum[row] + bias[col].
// ---------------------------------------------------------------------------
#define BK 64

template<int MODE, int MI, int NJ>
__global__ __launch_bounds__(256, 3)
void gemm_nt(const u16* __restrict__ A, const u16* __restrict__ Bt,
             void* __restrict__ Cout, const float* __restrict__ bias,
             float* __restrict__ rsum,
             int M, int N, int K, int lda, int ldb, int ldc,
             long sA, long sB, long sC, float escale)
{
  constexpr int BM = MI * 32;
  constexpr int BN = NJ * 32;
  __shared__ __align__(16) u16 As[BM * BK];
  __shared__ __align__(16) u16 Bs[BN * BK];

  const int bz = blockIdx.z;
  A  += (long)bz * sA;
  Bt += (long)bz * sB;

  const int tid  = threadIdx.x;
  const int wave = tid >> 6;
  const int lane = tid & 63;

  // GROUP_M=8 swizzle
  const int nbx = gridDim.x, nby = gridDim.y;
  const int pid  = blockIdx.y * nbx + blockIdx.x;
  const int band = 8 * nbx;
  const int gid  = pid / band;
  const int fm   = gid * 8;
  const int gsz  = min(nby - fm, 8);
  const int pm   = fm + (pid % band) % gsz;
  const int pn   = (pid % band) / gsz;
  const int tileM = pm * BM;
  const int tileN = pn * BN;

  // staging: per instruction a wave covers 8 rows x 8 chunks (16B each)
  const int srow = lane >> 3;      // 0..7 row within 8-row group
  const int sj   = lane & 7;       // 0..7 dest chunk
  const int sjj  = sj ^ srow;      // swizzled source chunk

  // wave quadrant + mfma lane coords
  const int wm = (wave >> 1) * (MI * 16);
  const int wn = (wave & 1) * (NJ * 16);
  const int lc = lane & 15;        // A row / B col / C col
  const int lq = lane >> 4;        // quad

  floatx4 acc[MI][NJ];
  #pragma unroll
  for (int i = 0; i < MI; ++i)
    #pragma unroll
    for (int j = 0; j < NJ; ++j)
      acc[i][j] = (floatx4){0.f, 0.f, 0.f, 0.f};

  for (int k0 = 0; k0 < K; k0 += BK) {
    #pragma unroll
    for (int s = 0; s < MI; ++s) {
      const int rb = (wave * MI + s) * 8;
      gload_lds16(A + (long)(tileM + rb + srow) * lda + k0 + sjj * 8,
                  &As[rb * BK]);
    }
    #pragma unroll
    for (int s = 0; s < NJ; ++s) {
      const int rb = (wave * NJ + s) * 8;
      gload_lds16(Bt + (long)(tileN + rb + srow) * ldb + k0 + sjj * 8,
                  &Bs[rb * BK]);
    }
    __syncthreads();   // drains vmcnt(0) -> LDS valid

    #pragma unroll
    for (int kk = 0; kk < BK; kk += 32) {
      const int jcb = (kk >> 3) + lq;       // logical chunk for this quad
      short8 af[MI], bf[NJ];
      #pragma unroll
      for (int i = 0; i < MI; ++i) {
        const int m = wm + i * 16 + lc;
        af[i] = *(const short8*)&As[m * BK + ((jcb ^ (m & 7)) << 3)];
      }
      #pragma unroll
      for (int j = 0; j < NJ; ++j) {
        const int n = wn + j * 16 + lc;
        bf[j] = *(const short8*)&Bs[n * BK + ((jcb ^ (n & 7)) << 3)];
      }
      #pragma unroll
      for (int i = 0; i < MI; ++i)
        #pragma unroll
        for (int j = 0; j < NJ; ++j)
          acc[i][j] = __builtin_amdgcn_mfma_f32_16x16x32_bf16(
                          af[i], bf[j], acc[i][j], 0, 0, 0);
    }
    __syncthreads();   // protect LDS before next stage
  }

  // epilogue: C/D layout col = lane&15, row = quad*4 + reg
  if (MODE == 0) {
    u16* C = (u16*)Cout + (long)bz * sC;
    #pragma unroll
    for (int i = 0; i < MI; ++i) {
      const int rb = tileM + wm + i * 16 + lq * 4;
      #pragma unroll
      for (int j = 0; j < NJ; ++j) {
        const int col = tileN + wn + j * 16 + lc;
        #pragma unroll
        for (int r = 0; r < 4; ++r)
          C[(long)(rb + r) * ldc + col] = f2bf(acc[i][j][r]);
      }
    }
  } else if (MODE == 1) {
    u16* C = (u16*)Cout + (long)bz * sC;
    float* rs = rsum + (long)bz * M;
    #pragma unroll
    for (int i = 0; i < MI; ++i) {
      const int rb = tileM + wm + i * 16 + lq * 4;
      float rpart[4] = {0.f, 0.f, 0.f, 0.f};
      #pragma unroll
      for (int j = 0; j < NJ; ++j) {
        const int col = tileN + wn + j * 16 + lc;
        #pragma unroll
        for (int r = 0; r < 4; ++r) {
          float e = __expf(acc[i][j][r] * escale);
          C[(long)(rb + r) * ldc + col] = f2bf(e);
          rpart[r] += e;
        }
      }
      #pragma unroll
      for (int r = 0; r < 4; ++r) {
        float s = rpart[r];
        s += __shfl_xor(s, 1, 64);
        s += __shfl_xor(s, 2, 64);
        s += __shfl_xor(s, 4, 64);
        s += __shfl_xor(s, 8, 64);
        if (lc == 0) atomicAdd(&rs[rb + r], s);
      }
    }
  } else {
    float* C = (float*)Cout + (long)bz * sC;
    const float* rs = rsum + (long)bz * M;
    #pragma unroll
    for (int i = 0; i < MI; ++i) {
      const int rb = tileM + wm + i * 16 + lq * 4;
      float inv[4];
      #pragma unroll
      for (int r = 0; r < 4; ++r) inv[r] = 1.0f / rs[rb + r];
      #pragma unroll
      for (int j = 0; j < NJ; ++j) {
        const int col = tileN + wn + j * 16 + lc;
        const float bv = bias[col];
        #pragma unroll
        for (int r = 0; r < 4; ++r)
          C[(long)(rb + r) * ldc + col] = acc[i][j][r] * inv[r] + bv;
      }
    }
  }
}

// ---------------------------------------------------------------------------
extern "C" void kernel_launch(void* const* d_in, const int* in_sizes, int n_in,
                              void* d_out, int out_size, void* d_ws, size_t ws_size,
                              hipStream_t stream) {
  const float* x    = (const float*)d_in[0];   // [B,S,D] fp32
  const float* W    = (const float*)d_in[1];   // [D,D]   fp32
  const float* bias = (const float*)d_in[2];   // [D]     fp32
  float* out        = (float*)d_out;           // [B,S,D] fp32
  (void)in_sizes; (void)n_in; (void)out_size; (void)ws_size;

  const int B = 8, S = 2048, D = 1024;
  const long BSD = (long)B * S * D;            // 16,777,216

  // workspace layout (u16 elements): ~162 MiB + 64 KiB row sums
  u16* Xb  = (u16*)d_ws;            // [B,S,D] bf16 (x)
  u16* XbT = Xb  + BSD;             // [B,D,S] bf16 (x transposed per batch)
  u16* Qb  = XbT + BSD;             // [B,S,D] bf16 (Q, pre-scaled by 1/32)
  u16* Wt  = Qb  + BSD;             // [D,D]   bf16 (W^T * 1/sqrt(D))
  u16* Sc  = Wt  + (long)D * D;     // [B,S,S] bf16 (E = exp(scores), unnorm)
  float* rsum = (float*)(Sc + (long)B * S * S);  // [B,S] fp32 row sums

  dim3 blk(256);

  // prep: x->Xb+XbT, W->Wt (1/32 folded into Q), rsum=0 — one dispatch
  prep<<<dim3(D/64, S/64, B + 1), blk, 0, stream>>>(x, W, Xb, XbT, Wt, rsum);

  // GEMM1: Qb[BS,D] = Xb[BS,D] @ Wt[D,D]^T   (batches flattened)
  gemm_nt<0, 4, 4><<<dim3(D/128, (B*S)/128, 1), blk, 0, stream>>>(
      Xb, Wt, Qb, nullptr, nullptr, B*S, D, D, D, D, D, 0, 0, 0, 1.0f);

  // GEMM2: Sc[S,S] = exp(Qb[S,D] @ Xb[S,D]^T), rsum += row sums  per batch
  gemm_nt<1, 4, 4><<<dim3(S/128, S/128, B), blk, 0, stream>>>(
      Qb, Xb, Sc, nullptr, rsum, S, S, D, D, D, S,
      (long)S*D, (long)S*D, (long)S*S, 1.0f);

  // GEMM3: out[S,D] = (Sc/rsum)[S,S] @ XbT[D,S]^T + bias  per batch, fp32 out
  gemm_nt<2, 4, 4><<<dim3(D/128, S/128, B), blk, 0, stream>>>(
      Sc, XbT, out, bias, rsum, S, D, S, S, S, D,
      (long)S*S, (long)D*S, (long)S*D, 1.0f);
}